// Round 13
// baseline (417.306 us; speedup 1.0000x reference)
//
#include <hip/hip_runtime.h>
#include <hip/hip_bf16.h>
#include <math.h>

// KoLeo loss, MI355X. Fused normalize+pack -> MFMA gram two-sided row-max
// (symmetric triangular walk, never materializes the gram) -> log/mean.
//
// v13: corrected MFMA model (32x32x16 = ~32.3 cyc/SIMD -> ONE wave/SIMD can
// saturate the matrix pipe with 4 chains). So: 1 block/CU, 1 wave/SIMD,
// 512-reg budget, and T15 acc ping-pong done flat (named sets, macros, no
// lambdas/refs -> no v10 spill): EPI(s-1) issues inside MFMA(s)'s window.
// Triple-buffer LDS (3x32KB) with counted vmcnt(10): stage(s+2) each iter,
// two full iterations of latency slack. knorm+kpack fused; memset folded in.
//
// F layout (32-row tiles): chunk(t32,ks,lane) = t32*1024 + ks*64 + lane,
//   16B chunk = 8 bf16 of xn[t32*32 + (lane&31)][ks*16 + (lane>>5)*8 .. +7].
// == mfma_f32_32x32x16_bf16 A/B fragment layout -> linear coalesced staging.
// D = mfma(bfr_i, af_j): col=lane&31 -> j_local, row=(r&3)+8(r>>2)+4(lane>>5)
// -> i_local (verified v8-v12, absmax 0).

typedef __attribute__((ext_vector_type(8))) short bf16x8;    // 8 bf16 = 4 VGPR
typedef __attribute__((ext_vector_type(16))) float f32x16;   // 32x32 acc

#define NROWS 16384
#define NDIM  256
#define NBLK  256
// pair-units: ib in [0,64) (256-row i-panel), jp in [4*ib, 256) (64-row j-pair)
// P(ib) = 2*ib*(129-ib); total 8320 units; 32.5 per block.

// ---------------- K0: fused row-norm + pack + rowcand zero ----------------
__device__ inline unsigned bf_rne(float f) {
    union { float f; unsigned u; } c; c.f = f;
    return (c.u + 0x7FFFu + ((c.u >> 16) & 1u)) >> 16;
}
__device__ inline unsigned pack2(float lo, float hi) {
    return bf_rne(lo) | (bf_rne(hi) << 16);
}

__global__ __launch_bounds__(256) void knp(const float* __restrict__ x,
                                           uint4* __restrict__ F,
                                           unsigned* __restrict__ rowcand) {
    __shared__ float rnorm[32];
    const int t32 = blockIdx.x;                     // 512 tiles of 32 rows
    const int tid = threadIdx.x;

    if (tid < 32) rowcand[t32 * 32 + tid] = 0u;     // zero my slice

    // norms: 8 threads per row, 32 floats each
    int row = tid >> 3;
    int c0  = (tid & 7) * 32;
    const float4* xr = (const float4*)(x + ((size_t)t32 * 32 + row) * NDIM + c0);
    float ss = 0.f;
    #pragma unroll
    for (int q = 0; q < 8; ++q) {
        float4 v = xr[q];
        ss += v.x * v.x + v.y * v.y + v.z * v.z + v.w * v.w;
    }
    ss += __shfl_xor(ss, 1, 64);
    ss += __shfl_xor(ss, 2, 64);
    ss += __shfl_xor(ss, 4, 64);
    if ((tid & 7) == 0) rnorm[row] = 1.0f / fmaxf(sqrtf(ss), 1e-12f);
    __syncthreads();

    // pack 1024 fragment chunks (4 per thread), coalesced
    #pragma unroll
    for (int q = 0; q < 4; ++q) {
        int c    = q * 256 + tid;
        int ks   = c >> 6;
        int lane = c & 63;
        int r    = lane & 31;
        int kb   = ks * 16 + (lane >> 5) * 8;
        float s  = rnorm[r];
        const float4* xp = (const float4*)(x + ((size_t)t32 * 32 + r) * NDIM + kb);
        float4 a = xp[0], b2 = xp[1];
        uint4 o;
        o.x = pack2(a.x * s, a.y * s);
        o.y = pack2(a.z * s, a.w * s);
        o.z = pack2(b2.x * s, b2.y * s);
        o.w = pack2(b2.z * s, b2.w * s);
        F[(size_t)t32 * 1024 + c] = o;
    }
}

// ---------------- helpers ----------------
__device__ inline void stage16(const uint4* __restrict__ g, const uint4* l) {
    __builtin_amdgcn_global_load_lds(
        (const __attribute__((address_space(1))) unsigned*)g,
        (__attribute__((address_space(3))) unsigned*)l, 16, 0, 0);
}

__device__ inline unsigned fkey(float f) {          // order-preserving key
    unsigned u = __builtin_bit_cast(unsigned, f);
    return (u & 0x80000000u) ? ~u : (u | 0x80000000u);
}

template<int CTRL>                                  // DPP rotate within 16-lane row
__device__ inline float dpp_rot(float x) {
    int xi = __builtin_bit_cast(int, x);
    int yi = __builtin_amdgcn_update_dpp(xi, xi, CTRL, 0xF, 0xF, false);
    return __builtin_bit_cast(float, yi);
}

// ---------------- K2: T15 ping-pong symmetric gram + two-sided max --------
// 256 blocks x 256 threads (4 waves, 1 block/CU, 1 wave/SIMD).
__global__ __launch_bounds__(256, 1) void kmax(const bf16x8* __restrict__ F,
                                               unsigned* __restrict__ rowcand) {
    __shared__ uint4 sbuf[3][2048];                 // 3 x 32KB j-pair buffers

    const int tid  = threadIdx.x;
    const int wid  = tid >> 6;                      // 0..3
    const int lane = tid & 63;
    const int L    = lane & 31;
    const int hi   = lane >> 5;
    const uint4* F4 = (const uint4*)F;

    const int b    = ((blockIdx.x & 7) << 5) | (blockIdx.x >> 3);  // XCD swz
    const int u0   = (b * 65) >> 1;                 // 8320/256 = 32.5
    const int uend = ((b + 1) * 65) >> 1;

    int cib = 0;                                    // decode u0 -> (cib, cjp)
    while (2 * (cib + 1) * (129 - (cib + 1)) <= u0) ++cib;
    int cjp = 4 * cib + (u0 - 2 * cib * (129 - cib));

    bf16x8 bfr0[16], bfr1[16];                      // hoisted i-frags, 128 regs
    int lib = cib;
    {
        int it = cib * 8 + 2 * wid;
        #pragma unroll
        for (int ks = 0; ks < 16; ++ks) {
            bfr0[ks] = F[(it + 0) * 1024 + ks * 64 + lane];
            bfr1[ks] = F[(it + 1) * 1024 + ks * 64 + lane];
        }
    }

    // prologue: stage(u0)+dummy, stage(u1)+dummy -> 10 newer than stage(u0)
    int sib = cib, sjp = cjp;
    {
        const uint4* gp = F4 + (size_t)sjp * 2048;
        #pragma unroll
        for (int q = 0; q < 8; ++q)
            stage16(gp + q * 256 + tid, &sbuf[0][q * 256 + wid * 64]);
    }
    atomicMax(&rowcand[0], 0u);
    if (++sjp == 256) { ++sib; sjp = 4 * sib; }
    {
        const uint4* gp = F4 + (size_t)sjp * 2048;
        #pragma unroll
        for (int q = 0; q < 8; ++q)
            stage16(gp + q * 256 + tid, &sbuf[1][q * 256 + wid * 64]);
    }
    atomicMax(&rowcand[0], 0u);

    float rm0[16], rm1[16];
    #pragma unroll
    for (int r = 0; r < 16; ++r) { rm0[r] = -1e30f; rm1[r] = -1e30f; }

    const bool dvalid = (((L >> 2) & 1) == hi);
    const int  dreg   = (L & 3) | ((L >> 3) << 2);
    const f32x16 zc = {0.f};

    auto flush_i = [&](int fib) {                   // fold rm over j, flush
        #pragma unroll
        for (int r = 0; r < 16; ++r) {
            float a = rm0[r];
            a = fmaxf(a, dpp_rot<0x121>(a));
            a = fmaxf(a, dpp_rot<0x122>(a));
            a = fmaxf(a, dpp_rot<0x124>(a));
            a = fmaxf(a, dpp_rot<0x128>(a));
            rm0[r] = fmaxf(a, __shfl_xor(a, 16, 64));
            float c = rm1[r];
            c = fmaxf(c, dpp_rot<0x121>(c));
            c = fmaxf(c, dpp_rot<0x122>(c));
            c = fmaxf(c, dpp_rot<0x124>(c));
            c = fmaxf(c, dpp_rot<0x128>(c));
            rm1[r] = fmaxf(c, __shfl_xor(c, 16, 64));
        }
        float v0 = rm0[0], v1 = rm1[0];
        #pragma unroll
        for (int r = 1; r < 16; ++r) {
            v0 = (dreg == r) ? rm0[r] : v0;
            v1 = (dreg == r) ? rm1[r] : v1;
        }
        if (dvalid) {
            int base = fib * 256 + wid * 64;
            atomicMax(&rowcand[base + L],      fkey(v0));
            atomicMax(&rowcand[base + 32 + L], fkey(v1));
        }
    };

    f32x16 cA00, cA01, cA10, cA11;                  // two named acc sets
    f32x16 cB00, cB01, cB10, cB11;
    int jpA = 0, ibA = 0, jpB = 0, ibB = 0;
    bool pdA = false, pdB = false;
    int bsel = 0;

// EPI on set X for unit meta (PJP,PPD,PIB); CURIB = ib of unit being MFMA'd
#define EPI(X00, X01, X10, X11, PJP, PPD, PIB, CURIB)                        \
    do {                                                                     \
        float jm0 = -1e30f, jm1 = -1e30f;                                    \
        if (PPD) {                                                           \
            _Pragma("unroll")                                                \
            for (int r = 0; r < 16; ++r) {                                   \
                float v00 = X00[r], v11 = X11[r];                            \
                if (dvalid && r == dreg) { v00 = -1e30f; v11 = -1e30f; }     \
                rm0[r] = fmaxf(rm0[r], fmaxf(v00, X01[r]));                  \
                rm1[r] = fmaxf(rm1[r], fmaxf(X10[r], v11));                  \
                jm0 = fmaxf(jm0, fmaxf(v00, X10[r]));                        \
                jm1 = fmaxf(jm1, fmaxf(X01[r], v11));                        \
            }                                                                \
        } else {                                                             \
            _Pragma("unroll")                                                \
            for (int r = 0; r < 16; ++r) {                                   \
                rm0[r] = fmaxf(rm0[r], fmaxf(X00[r], X01[r]));               \
                rm1[r] = fmaxf(rm1[r], fmaxf(X10[r], X11[r]));               \
                jm0 = fmaxf(jm0, fmaxf(X00[r], X10[r]));                     \
                jm1 = fmaxf(jm1, fmaxf(X01[r], X11[r]));                     \
            }                                                                \
        }                                                                    \
        jm0 = fmaxf(jm0, __shfl_xor(jm0, 32, 64));                           \
        jm1 = fmaxf(jm1, __shfl_xor(jm1, 32, 64));                           \
        float js = hi ? jm1 : jm0;                                           \
        atomicMax(&rowcand[(PJP) * 64 + lane], fkey(js));                    \
        if ((PIB) != (CURIB)) {                                              \
            flush_i(PIB);                                                    \
            _Pragma("unroll")                                                \
            for (int r = 0; r < 16; ++r) { rm0[r] = -1e30f; rm1[r] = -1e30f; } \
        }                                                                    \
    } while (0)

// one pipeline step: MFMA into set C, EPI on set P (if HAVEP)
#define STEP(C00, C01, C10, C11, MJP, MPD, MIB,                              \
             P00, P01, P10, P11, PJP, PPD, PIB, HAVEP)                       \
    do {                                                                     \
        asm volatile("s_waitcnt vmcnt(10)" ::: "memory");                    \
        __builtin_amdgcn_s_barrier();                                        \
        __builtin_amdgcn_sched_barrier(0);                                   \
        if (cib != lib) {                                                    \
            int it = cib * 8 + 2 * wid;                                      \
            _Pragma("unroll")                                                \
            for (int ks = 0; ks < 16; ++ks) {                                \
                bfr0[ks] = F[(it + 0) * 1024 + ks * 64 + lane];              \
                bfr1[ks] = F[(it + 1) * 1024 + ks * 64 + lane];              \
            }                                                                \
            lib = cib;                                                       \
        }                                                                    \
        MJP = cjp; MPD = (cjp == cib * 4 + wid); MIB = cib;                  \
        const uint4* sb = &sbuf[bsel][0];                                    \
        {                                                                    \
            bf16x8 af0 = *(const bf16x8*)(sb + lane);                        \
            bf16x8 af1 = *(const bf16x8*)(sb + 1024 + lane);                 \
            C00 = __builtin_amdgcn_mfma_f32_32x32x16_bf16(bfr0[0], af0, zc, 0, 0, 0); \
            C10 = __builtin_amdgcn_mfma_f32_32x32x16_bf16(bfr1[0], af0, zc, 0, 0, 0); \
            C01 = __builtin_amdgcn_mfma_f32_32x32x16_bf16(bfr0[0], af1, zc, 0, 0, 0); \
            C11 = __builtin_amdgcn_mfma_f32_32x32x16_bf16(bfr1[0], af1, zc, 0, 0, 0); \
        }                                                                    \
        _Pragma("unroll")                                                    \
        for (int ks = 1; ks < 16; ++ks) {                                    \
            bf16x8 af0 = *(const bf16x8*)(sb + ks * 64 + lane);              \
            bf16x8 af1 = *(const bf16x8*)(sb + 1024 + ks * 64 + lane);       \
            C00 = __builtin_amdgcn_mfma_f32_32x32x16_bf16(bfr0[ks], af0, C00, 0, 0, 0); \
            C10 = __builtin_amdgcn_mfma_f32_32x32x16_bf16(bfr1[ks], af0, C10, 0, 0, 0); \
            C01 = __builtin_amdgcn_mfma_f32_32x32x16_bf16(bfr0[ks], af1, C01, 0, 0, 0); \
            C11 = __builtin_amdgcn_mfma_f32_32x32x16_bf16(bfr1[ks], af1, C11, 0, 0, 0); \
        }                                                                    \
        if (++sjp == 256) { if (sib < 63) { ++sib; sjp = 4 * sib; } else sjp = 255; } \
        {                                                                    \
            int ssl = bsel + 2; if (ssl >= 3) ssl -= 3;                      \
            const uint4* gp = F4 + (size_t)sjp * 2048;                       \
            uint4* dst = &sbuf[ssl][0];                                      \
            _Pragma("unroll")                                                \
            for (int q = 0; q < 8; ++q)                                      \
                stage16(gp + q * 256 + tid, dst + q * 256 + wid * 64);       \
        }                                                                    \
        __builtin_amdgcn_sched_barrier(0x7); /* ALU may cross; VMEM pinned */\
        if (HAVEP) EPI(P00, P01, P10, P11, PJP, PPD, PIB, MIB);              \
        else       atomicMax(&rowcand[0], 0u);                               \
        if (++cjp == 256) { if (cib < 63) { ++cib; cjp = 4 * cib; } else cjp = 255; } \
        bsel = (bsel == 2) ? 0 : bsel + 1;                                   \
    } while (0)

    const int n = uend - u0;
    for (int s = 0; s < n; ++s) {
        if (!(s & 1)) STEP(cA00, cA01, cA10, cA11, jpA, pdA, ibA,
                           cB00, cB01, cB10, cB11, jpB, pdB, ibB, (s > 0));
        else          STEP(cB00, cB01, cB10, cB11, jpB, pdB, ibB,
                           cA00, cA01, cA10, cA11, jpA, pdA, ibA, true);
    }
    // drain: EPI on the last MFMA'd set, then final i-flush
    if (n & 1) { EPI(cA00, cA01, cA10, cA11, jpA, pdA, ibA, ibA); flush_i(ibA); }
    else       { EPI(cB00, cB01, cB10, cB11, jpB, pdB, ibB, ibB); flush_i(ibB); }
#undef STEP
#undef EPI
}

// ---------------- K3: loss epilogue (2-stage, deterministic) --------------
__global__ __launch_bounds__(256) void kloss1(const unsigned* __restrict__ rowcand,
                                              float* __restrict__ partial) {
    int i = blockIdx.x * 256 + threadIdx.x;         // 64 blocks x 256
    unsigned k = rowcand[i];
    unsigned u = (k & 0x80000000u) ? (k ^ 0x80000000u) : ~k;
    float gv = __builtin_bit_cast(float, u);
    float d = sqrtf(fmaxf(2.f - 2.f * gv, 0.f));
    float acc = logf(d + 1e-8f);
    #pragma unroll
    for (int m = 1; m < 64; m <<= 1) acc += __shfl_xor(acc, m, 64);
    __shared__ float p[4];
    int wid = threadIdx.x >> 6, lane = threadIdx.x & 63;
    if (lane == 0) p[wid] = acc;
    __syncthreads();
    if (threadIdx.x == 0)
        partial[blockIdx.x] = (p[0] + p[1]) + (p[2] + p[3]);
}

__global__ __launch_bounds__(64) void kloss2(const float* __restrict__ partial,
                                             float* __restrict__ out) {
    float acc = partial[threadIdx.x];
    #pragma unroll
    for (int m = 1; m < 64; m <<= 1) acc += __shfl_xor(acc, m, 64);
    if (threadIdx.x == 0) out[0] = -acc / (float)NROWS;
}

extern "C" void kernel_launch(void* const* d_in, const int* in_sizes, int n_in,
                              void* d_out, int out_size, void* d_ws, size_t ws_size,
                              hipStream_t stream) {
    const float* x = (const float*)d_in[0];
    float* out = (float*)d_out;
    char* ws = (char*)d_ws;

    uint4*    F       = (uint4*)ws;                                 // 8 MiB
    unsigned* rowcand = (unsigned*)(ws + 8u * 1024u * 1024u + 65536u); // 64 KiB
    float*    partial = (float*)(ws + 8u * 1024u * 1024u + 131072u);   // 256 B

    knp   <<<NROWS / 32, 256, 0, stream>>>(x, F, rowcand);
    kmax  <<<NBLK, 256, 0, stream>>>((const bf16x8*)F, rowcand);
    kloss1<<<64, 256, 0, stream>>>(rowcand, partial);
    kloss2<<<1, 64, 0, stream>>>(partial, out);
}

// Round 14
// 97.708 us; speedup vs baseline: 4.2709x; 4.2709x over previous
//
#include <hip/hip_runtime.h>
#include <hip/hip_bf16.h>
#include <math.h>

// KoLeo loss, MI355X. Fused normalize+pack -> MFMA gram two-sided row-max
// (symmetric triangular walk, never materializes the gram) -> log/mean.
//
// v14: QUAD units (256i x 128j) with a SINGLE acc set of 8 chains (128 AGPR
// -- EPI reads via accvgpr_read, no second set -> no v10/v13 spill):
//   - per iteration 128 MFMA/wave (4132 cyc/SIMD) vs ~fixed 1-2k overhead
//     -> overhead amortized 2x vs pair-units; 16.25 iterations per CU.
//   - double-buffered LDS (2 x 64KB); stage(s+1) issued FIRST after the
//     barrier (its slot's readers finished at iter s-1), counted vmcnt(1).
//   - diag masking: <=2 diag chains per wave, wave-uniform fast/slow path.
//
// F layout (32-row tiles): chunk(t32,ks,lane) = t32*1024 + ks*64 + lane,
//   16B chunk = 8 bf16 of xn[t32*32 + (lane&31)][ks*16 + (lane>>5)*8 .. +7].
// == mfma_f32_32x32x16_bf16 A/B fragment layout -> linear coalesced staging.
// D = mfma(bfr_i, af_j): col=lane&31 -> j_local, row=(r&3)+8(r>>2)+4(lane>>5)
// -> i_local (verified v8-v13, absmax 0 throughout).

typedef __attribute__((ext_vector_type(8))) short bf16x8;    // 8 bf16 = 4 VGPR
typedef __attribute__((ext_vector_type(16))) float f32x16;   // 32x32 acc

#define NROWS 16384
#define NDIM  256
#define NBLK  256
// quad-units: ib in [0,64) (256-row i-panel), jq in [2*ib, 128) (128-row j)
// P(ib) = ib*(129-ib); total 4160 units; 16.25 per block.

// ---------------- K0: fused row-norm + pack + rowcand zero ----------------
__device__ inline unsigned bf_rne(float f) {
    union { float f; unsigned u; } c; c.f = f;
    return (c.u + 0x7FFFu + ((c.u >> 16) & 1u)) >> 16;
}
__device__ inline unsigned pack2(float lo, float hi) {
    return bf_rne(lo) | (bf_rne(hi) << 16);
}

__global__ __launch_bounds__(256) void knp(const float* __restrict__ x,
                                           uint4* __restrict__ F,
                                           unsigned* __restrict__ rowcand) {
    __shared__ float rnorm[32];
    const int t32 = blockIdx.x;                     // 512 tiles of 32 rows
    const int tid = threadIdx.x;

    if (tid < 32) rowcand[t32 * 32 + tid] = 0u;     // zero my slice

    int row = tid >> 3;                             // 8 threads per row
    int c0  = (tid & 7) * 32;
    const float4* xr = (const float4*)(x + ((size_t)t32 * 32 + row) * NDIM + c0);
    float ss = 0.f;
    #pragma unroll
    for (int q = 0; q < 8; ++q) {
        float4 v = xr[q];
        ss += v.x * v.x + v.y * v.y + v.z * v.z + v.w * v.w;
    }
    ss += __shfl_xor(ss, 1, 64);
    ss += __shfl_xor(ss, 2, 64);
    ss += __shfl_xor(ss, 4, 64);
    if ((tid & 7) == 0) rnorm[row] = 1.0f / fmaxf(sqrtf(ss), 1e-12f);
    __syncthreads();

    #pragma unroll
    for (int q = 0; q < 4; ++q) {                   // 4 fragment chunks each
        int c    = q * 256 + tid;
        int ks   = c >> 6;
        int lane = c & 63;
        int r    = lane & 31;
        int kb   = ks * 16 + (lane >> 5) * 8;
        float s  = rnorm[r];
        const float4* xp = (const float4*)(x + ((size_t)t32 * 32 + r) * NDIM + kb);
        float4 a = xp[0], b2 = xp[1];
        uint4 o;
        o.x = pack2(a.x * s, a.y * s);
        o.y = pack2(a.z * s, a.w * s);
        o.z = pack2(b2.x * s, b2.y * s);
        o.w = pack2(b2.z * s, b2.w * s);
        F[(size_t)t32 * 1024 + c] = o;
    }
}

// ---------------- helpers ----------------
__device__ inline void stage16(const uint4* __restrict__ g, const uint4* l) {
    __builtin_amdgcn_global_load_lds(
        (const __attribute__((address_space(1))) unsigned*)g,
        (__attribute__((address_space(3))) unsigned*)l, 16, 0, 0);
}

__device__ inline unsigned fkey(float f) {          // order-preserving key
    unsigned u = __builtin_bit_cast(unsigned, f);
    return (u & 0x80000000u) ? ~u : (u | 0x80000000u);
}

template<int CTRL>                                  // DPP rotate within 16-lane row
__device__ inline float dpp_rot(float x) {
    int xi = __builtin_bit_cast(int, x);
    int yi = __builtin_amdgcn_update_dpp(xi, xi, CTRL, 0xF, 0xF, false);
    return __builtin_bit_cast(float, yi);
}

// ---------------- K2: quad-unit symmetric gram + two-sided max ------------
// 256 blocks x 256 threads (4 waves, 1 block/CU). Unit = 256i x 128j rows.
__global__ __launch_bounds__(256, 1) void kmax(const bf16x8* __restrict__ F,
                                               unsigned* __restrict__ rowcand) {
    __shared__ uint4 sbuf[2][4096];                 // 2 x 64KB j-quad buffers

    const int tid  = threadIdx.x;
    const int wid  = tid >> 6;                      // 0..3
    const int lane = tid & 63;
    const int L    = lane & 31;
    const int hi   = lane >> 5;
    const uint4* F4 = (const uint4*)F;

    const int b    = ((blockIdx.x & 7) << 5) | (blockIdx.x >> 3);  // XCD swz
    const int u0   = (b * 65) >> 2;                 // 4160/256 = 16.25
    const int uend = ((b + 1) * 65) >> 2;

    int cib = 0;                                    // decode u0 -> (cib, cjq)
    while ((cib + 1) * (128 - cib) <= u0) ++cib;
    int cjq = 2 * cib + (u0 - cib * (129 - cib));

    bf16x8 bfr0[16], bfr1[16];                      // hoisted i-frags, 128 regs
    int lib = cib;
    {
        int it = cib * 8 + 2 * wid;
        #pragma unroll
        for (int ks = 0; ks < 16; ++ks) {
            bfr0[ks] = F[(it + 0) * 1024 + ks * 64 + lane];
            bfr1[ks] = F[(it + 1) * 1024 + ks * 64 + lane];
        }
    }

    // prologue: stage(u0) [16 loads] + 1 dummy atomic -> vmcnt(1) at iter 0
    {
        const uint4* gp = F4 + (size_t)cjq * 4096;
        #pragma unroll
        for (int q = 0; q < 16; ++q)
            stage16(gp + q * 256 + tid, &sbuf[0][q * 256 + wid * 64]);
    }
    atomicMax(&rowcand[0], 0u);

    float rm0[16], rm1[16];
    #pragma unroll
    for (int r = 0; r < 16; ++r) { rm0[r] = -1e30f; rm1[r] = -1e30f; }

    const bool dvalid = (((L >> 2) & 1) == hi);     // lane holds a diag elem
    const int  dreg   = (L & 3) | ((L >> 3) << 2);  // ...at this acc reg
    const f32x16 zc = {0.f};

    auto flush_i = [&](int fib) {                   // fold rm over j, flush
        #pragma unroll
        for (int r = 0; r < 16; ++r) {
            float a = rm0[r];
            a = fmaxf(a, dpp_rot<0x121>(a));
            a = fmaxf(a, dpp_rot<0x122>(a));
            a = fmaxf(a, dpp_rot<0x124>(a));
            a = fmaxf(a, dpp_rot<0x128>(a));
            rm0[r] = fmaxf(a, __shfl_xor(a, 16, 64));
            float c = rm1[r];
            c = fmaxf(c, dpp_rot<0x121>(c));
            c = fmaxf(c, dpp_rot<0x122>(c));
            c = fmaxf(c, dpp_rot<0x124>(c));
            c = fmaxf(c, dpp_rot<0x128>(c));
            rm1[r] = fmaxf(c, __shfl_xor(c, 16, 64));
        }
        float v0 = rm0[0], v1 = rm1[0];
        #pragma unroll
        for (int r = 1; r < 16; ++r) {
            v0 = (dreg == r) ? rm0[r] : v0;         // lane picks its i-row
            v1 = (dreg == r) ? rm1[r] : v1;
        }
        if (dvalid) {
            int base = fib * 256 + wid * 64;
            atomicMax(&rowcand[base + L],      fkey(v0));
            atomicMax(&rowcand[base + 32 + L], fkey(v1));
        }
    };

    int bsel = 0;
    for (int s = u0; s < uend; ++s) {
        asm volatile("s_waitcnt vmcnt(1)" ::: "memory");
        __builtin_amdgcn_s_barrier();
        __builtin_amdgcn_sched_barrier(0);

        if (cib != lib) {                           // rare i-panel change
            int it = cib * 8 + 2 * wid;
            #pragma unroll
            for (int ks = 0; ks < 16; ++ks) {
                bfr0[ks] = F[(it + 0) * 1024 + ks * 64 + lane];
                bfr1[ks] = F[(it + 1) * 1024 + ks * 64 + lane];
            }
            lib = cib;
        }

        // next-unit coords; stage it FIRST (slot bsel^1: readers done at s-1)
        int nib = cib, njq = cjq + 1;
        if (njq == 128) { if (nib < 63) { ++nib; njq = 2 * nib; } else njq = 127; }
        {
            const uint4* gp = F4 + (size_t)njq * 4096;
            uint4* dst = &sbuf[bsel ^ 1][0];
            #pragma unroll
            for (int q = 0; q < 16; ++q)
                stage16(gp + q * 256 + tid, dst + q * 256 + wid * 64);
        }

        // ---- MFMA: 8 independent chains over 4 j-tiles x 2 i-tiles ----
        const uint4* sb = &sbuf[bsel][0];
        f32x16 c00, c01, c02, c03, c10, c11, c12, c13;
        {
            bf16x8 a0 = *(const bf16x8*)(sb + lane);
            bf16x8 a1 = *(const bf16x8*)(sb + 1024 + lane);
            bf16x8 a2 = *(const bf16x8*)(sb + 2048 + lane);
            bf16x8 a3 = *(const bf16x8*)(sb + 3072 + lane);
            c00 = __builtin_amdgcn_mfma_f32_32x32x16_bf16(bfr0[0], a0, zc, 0, 0, 0);
            c10 = __builtin_amdgcn_mfma_f32_32x32x16_bf16(bfr1[0], a0, zc, 0, 0, 0);
            c01 = __builtin_amdgcn_mfma_f32_32x32x16_bf16(bfr0[0], a1, zc, 0, 0, 0);
            c11 = __builtin_amdgcn_mfma_f32_32x32x16_bf16(bfr1[0], a1, zc, 0, 0, 0);
            c02 = __builtin_amdgcn_mfma_f32_32x32x16_bf16(bfr0[0], a2, zc, 0, 0, 0);
            c12 = __builtin_amdgcn_mfma_f32_32x32x16_bf16(bfr1[0], a2, zc, 0, 0, 0);
            c03 = __builtin_amdgcn_mfma_f32_32x32x16_bf16(bfr0[0], a3, zc, 0, 0, 0);
            c13 = __builtin_amdgcn_mfma_f32_32x32x16_bf16(bfr1[0], a3, zc, 0, 0, 0);
        }
        #pragma unroll
        for (int ks = 1; ks < 16; ++ks) {
            bf16x8 a0 = *(const bf16x8*)(sb + ks * 64 + lane);
            bf16x8 a1 = *(const bf16x8*)(sb + 1024 + ks * 64 + lane);
            bf16x8 a2 = *(const bf16x8*)(sb + 2048 + ks * 64 + lane);
            bf16x8 a3 = *(const bf16x8*)(sb + 3072 + ks * 64 + lane);
            c00 = __builtin_amdgcn_mfma_f32_32x32x16_bf16(bfr0[ks], a0, c00, 0, 0, 0);
            c10 = __builtin_amdgcn_mfma_f32_32x32x16_bf16(bfr1[ks], a0, c10, 0, 0, 0);
            c01 = __builtin_amdgcn_mfma_f32_32x32x16_bf16(bfr0[ks], a1, c01, 0, 0, 0);
            c11 = __builtin_amdgcn_mfma_f32_32x32x16_bf16(bfr1[ks], a1, c11, 0, 0, 0);
            c02 = __builtin_amdgcn_mfma_f32_32x32x16_bf16(bfr0[ks], a2, c02, 0, 0, 0);
            c12 = __builtin_amdgcn_mfma_f32_32x32x16_bf16(bfr1[ks], a2, c12, 0, 0, 0);
            c03 = __builtin_amdgcn_mfma_f32_32x32x16_bf16(bfr0[ks], a3, c03, 0, 0, 0);
            c13 = __builtin_amdgcn_mfma_f32_32x32x16_bf16(bfr1[ks], a3, c13, 0, 0, 0);
        }

        // ---- EPI: two-sided max with <=2 diag chains ----
        // diag chain (it, jt): 4*cjq + jt == 8*cib + 2*wid + it
        const int  dq      = cjq - 2 * cib;
        const bool hasdiag = (dq <= 1) && (dq == (wid >> 1));
        const int  jd0     = 2 * wid - 4 * dq;      // it=0 diag tile
        const int  jd1     = jd0 + 1;               // it=1 diag tile
        float jm0 = -1e30f, jm1 = -1e30f, jm2 = -1e30f, jm3 = -1e30f;

#define EPI_R(r, MASKED)                                                      \
        {                                                                     \
            float a0 = c00[r], a1 = c01[r], a2 = c02[r], a3 = c03[r];         \
            float b0 = c10[r], b1 = c11[r], b2 = c12[r], b3 = c13[r];         \
            if (MASKED) {                                                     \
                bool dr = dvalid && ((r) == dreg);                            \
                if (dr && jd0 == 0) a0 = -1e30f;                              \
                if (dr && jd0 == 1) a1 = -1e30f;                              \
                if (dr && jd0 == 2) a2 = -1e30f;                              \
                if (dr && jd0 == 3) a3 = -1e30f;                              \
                if (dr && jd1 == 1) b1 = -1e30f;                              \
                if (dr && jd1 == 2) b2 = -1e30f;                              \
                if (dr && jd1 == 3) b3 = -1e30f;                              \
            }                                                                 \
            rm0[r] = fmaxf(rm0[r], fmaxf(fmaxf(a0, a1), fmaxf(a2, a3)));      \
            rm1[r] = fmaxf(rm1[r], fmaxf(fmaxf(b0, b1), fmaxf(b2, b3)));      \
            jm0 = fmaxf(jm0, fmaxf(a0, b0));                                  \
            jm1 = fmaxf(jm1, fmaxf(a1, b1));                                  \
            jm2 = fmaxf(jm2, fmaxf(a2, b2));                                  \
            jm3 = fmaxf(jm3, fmaxf(a3, b3));                                  \
        }
        if (hasdiag) {
            #pragma unroll
            for (int r = 0; r < 16; ++r) EPI_R(r, true)
        } else {
            #pragma unroll
            for (int r = 0; r < 16; ++r) EPI_R(r, false)
        }
#undef EPI_R
        jm0 = fmaxf(jm0, __shfl_xor(jm0, 32, 64));  // fold i-halves
        jm1 = fmaxf(jm1, __shfl_xor(jm1, 32, 64));
        jm2 = fmaxf(jm2, __shfl_xor(jm2, 32, 64));
        jm3 = fmaxf(jm3, __shfl_xor(jm3, 32, 64));
        float jsA = hi ? jm1 : jm0;                 // tiles 0,1 on 64 lanes
        float jsB = hi ? jm3 : jm2;                 // tiles 2,3
        atomicMax(&rowcand[cjq * 128 + lane],      fkey(jsA));
        atomicMax(&rowcand[cjq * 128 + 64 + lane], fkey(jsB));

        if (nib != cib) {                           // i-panel transition
            flush_i(cib);
            #pragma unroll
            for (int r = 0; r < 16; ++r) { rm0[r] = -1e30f; rm1[r] = -1e30f; }
        }
        cib = nib; cjq = njq; bsel ^= 1;
    }
    flush_i(lib);   // final flush (harmless -1e30 keys if already flushed)
}

// ---------------- K3: loss epilogue (2-stage, deterministic) --------------
__global__ __launch_bounds__(256) void kloss1(const unsigned* __restrict__ rowcand,
                                              float* __restrict__ partial) {
    int i = blockIdx.x * 256 + threadIdx.x;         // 64 blocks x 256
    unsigned k = rowcand[i];
    unsigned u = (k & 0x80000000u) ? (k ^ 0x80000000u) : ~k;
    float gv = __builtin_bit_cast(float, u);
    float d = sqrtf(fmaxf(2.f - 2.f * gv, 0.f));
    float acc = logf(d + 1e-8f);
    #pragma unroll
    for (int m = 1; m < 64; m <<= 1) acc += __shfl_xor(acc, m, 64);
    __shared__ float p[4];
    int wid = threadIdx.x >> 6, lane = threadIdx.x & 63;
    if (lane == 0) p[wid] = acc;
    __syncthreads();
    if (threadIdx.x == 0)
        partial[blockIdx.x] = (p[0] + p[1]) + (p[2] + p[3]);
}

__global__ __launch_bounds__(64) void kloss2(const float* __restrict__ partial,
                                             float* __restrict__ out) {
    float acc = partial[threadIdx.x];
    #pragma unroll
    for (int m = 1; m < 64; m <<= 1) acc += __shfl_xor(acc, m, 64);
    if (threadIdx.x == 0) out[0] = -acc / (float)NROWS;
}

extern "C" void kernel_launch(void* const* d_in, const int* in_sizes, int n_in,
                              void* d_out, int out_size, void* d_ws, size_t ws_size,
                              hipStream_t stream) {
    const float* x = (const float*)d_in[0];
    float* out = (float*)d_out;
    char* ws = (char*)d_ws;

    uint4*    F       = (uint4*)ws;                                 // 8 MiB
    unsigned* rowcand = (unsigned*)(ws + 8u * 1024u * 1024u + 65536u); // 64 KiB
    float*    partial = (float*)(ws + 8u * 1024u * 1024u + 131072u);   // 256 B

    knp   <<<NROWS / 32, 256, 0, stream>>>(x, F, rowcand);
    kmax  <<<NBLK, 256, 0, stream>>>((const bf16x8*)F, rowcand);
    kloss1<<<64, 256, 0, stream>>>(rowcand, partial);
    kloss2<<<1, 64, 0, stream>>>(partial, out);
}